// Round 1
// baseline (1277.992 us; speedup 1.0000x reference)
//
#include <hip/hip_runtime.h>
#include <math.h>

// Problem constants (from reference): B=2, S=2048, E=1024, H=16, D=64
#define B_ 2
#define S_ 2048
#define E_ 1024
#define H_ 16
#define D_ 64
#define M_ (B_ * S_)   // 4096 rows of the token matrix
#define K_ E_          // 1024 reduction dim for projections

// LDS row stride: 68 floats = 272 B (16B-aligned for float4, and 68%32=4 ->
// the 16-wide b128 read pattern covers all 32 banks 2-way = free per m136).
#define LSTR 68

// ---------------------------------------------------------------------------
// GEMM: Y[m][n] = sum_k X[m][k] * W[n][k] + bias[n]   (torch Linear: x @ W^T + b)
// 64x64 output tile per 256-thread block, 4x4 per thread, BK=64.
// head_split=1: scatter into [B,H,S,D] (n-tile == head h since N/64 == H).
// head_split=0: plain row-major [M, E] store (final projection -> d_out).
// ---------------------------------------------------------------------------
__global__ __launch_bounds__(256)
void gemm_xwt(const float* __restrict__ X, const float* __restrict__ W,
              const float* __restrict__ bias, float* __restrict__ Y,
              int head_split)
{
    __shared__ float Ast[64][LSTR];  // [k][m] transposed A tile
    __shared__ float Bst[64][LSTR];  // [k][n] transposed B tile

    const int tid = threadIdx.x;
    const int tx = tid & 15;         // n sub-tile
    const int ty = tid >> 4;         // m sub-tile
    const int m0 = blockIdx.y * 64;
    const int n0 = blockIdx.x * 64;

    float acc[4][4] = {};

    for (int k0 = 0; k0 < K_; k0 += 64) {
        // Stage 64x64 tiles of A (X rows) and B (W rows), transposed into LDS.
        #pragma unroll
        for (int i = 0; i < 4; ++i) {
            const int row = (tid >> 4) + i * 16;   // 0..63
            const int col = (tid & 15) * 4;        // 0..60, step 4 (k within tile)
            const float4 a = *(const float4*)(X + (size_t)(m0 + row) * K_ + k0 + col);
            Ast[col + 0][row] = a.x;
            Ast[col + 1][row] = a.y;
            Ast[col + 2][row] = a.z;
            Ast[col + 3][row] = a.w;
            const float4 b = *(const float4*)(W + (size_t)(n0 + row) * K_ + k0 + col);
            Bst[col + 0][row] = b.x;
            Bst[col + 1][row] = b.y;
            Bst[col + 2][row] = b.z;
            Bst[col + 3][row] = b.w;
        }
        __syncthreads();

        #pragma unroll 8
        for (int kk = 0; kk < 64; ++kk) {
            const float4 a4 = *(const float4*)&Ast[kk][ty * 4];
            const float4 b4 = *(const float4*)&Bst[kk][tx * 4];
            const float a[4] = {a4.x, a4.y, a4.z, a4.w};
            const float b[4] = {b4.x, b4.y, b4.z, b4.w};
            #pragma unroll
            for (int i = 0; i < 4; ++i)
                #pragma unroll
                for (int j = 0; j < 4; ++j)
                    acc[i][j] += a[i] * b[j];
        }
        __syncthreads();
    }

    // Epilogue: bias + store
    const float4 bb = *(const float4*)(bias + n0 + tx * 4);
    const float bj[4] = {bb.x, bb.y, bb.z, bb.w};

    #pragma unroll
    for (int i = 0; i < 4; ++i) {
        const int m = m0 + ty * 4 + i;
        float4 o;
        o.x = acc[i][0] + bj[0];
        o.y = acc[i][1] + bj[1];
        o.z = acc[i][2] + bj[2];
        o.w = acc[i][3] + bj[3];
        if (head_split) {
            // n0 is 64-aligned and N==H*64, so h = n0/64, d = tx*4..
            const int bb_ = m >> 11;        // m / S_
            const int s  = m & (S_ - 1);
            const int h  = n0 >> 6;
            float* dst = Y + (((size_t)(bb_ * H_ + h) * S_ + s) * D_) + tx * 4;
            *(float4*)dst = o;
        } else {
            *(float4*)(Y + (size_t)m * E_ + n0 + tx * 4) = o;
        }
    }
}

// ---------------------------------------------------------------------------
// Flash attention (fp32, online softmax). One block per (q-tile=64, head, batch).
// Q/K staged transposed [k][m]; V natural [j][d]; P stored transposed [j][r].
// ---------------------------------------------------------------------------
__global__ __launch_bounds__(256)
void flash_attn(const float* __restrict__ Qg, const float* __restrict__ Kg,
                const float* __restrict__ Vg, float* __restrict__ Og)
{
    __shared__ float Qst[D_][LSTR];   // [k][m], pre-scaled by 1/sqrt(D)
    __shared__ float Kst[D_][LSTR];   // [k][n]
    __shared__ float Vs[64][LSTR];    // [j][d]
    __shared__ float Pst[64][LSTR];   // [j][r]  (scores then probabilities, transposed)
    __shared__ float m_s[64], l_s[64], alpha_s[64];

    const int tid = threadIdx.x;
    const int tx = tid & 15;
    const int ty = tid >> 4;
    const int q0 = blockIdx.x * 64;
    const int h  = blockIdx.y;
    const int b  = blockIdx.z;
    const size_t head_off = (size_t)(b * H_ + h) * S_ * D_;
    const float scale = 0.125f;  // 1/sqrt(64)

    // Load Q tile (transposed, pre-scaled)
    #pragma unroll
    for (int i = 0; i < 4; ++i) {
        const int row = (tid >> 4) + i * 16;
        const int col = (tid & 15) * 4;
        const float4 a = *(const float4*)(Qg + head_off + (size_t)(q0 + row) * D_ + col);
        Qst[col + 0][row] = a.x * scale;
        Qst[col + 1][row] = a.y * scale;
        Qst[col + 2][row] = a.z * scale;
        Qst[col + 3][row] = a.w * scale;
    }
    if (tid < 64) { m_s[tid] = -1e30f; l_s[tid] = 0.0f; }
    float o_acc[4][4] = {};
    __syncthreads();

    for (int j0 = 0; j0 < S_; j0 += 64) {
        // Stage K (transposed) and V (natural)
        #pragma unroll
        for (int i = 0; i < 4; ++i) {
            const int row = (tid >> 4) + i * 16;
            const int col = (tid & 15) * 4;
            const float4 kk4 = *(const float4*)(Kg + head_off + (size_t)(j0 + row) * D_ + col);
            Kst[col + 0][row] = kk4.x;
            Kst[col + 1][row] = kk4.y;
            Kst[col + 2][row] = kk4.z;
            Kst[col + 3][row] = kk4.w;
            const float4 v4 = *(const float4*)(Vg + head_off + (size_t)(j0 + row) * D_ + col);
            *(float4*)&Vs[row][col] = v4;
        }
        __syncthreads();

        // Scores: sc[i][j] = (q_r . k_c) * scale  (scale folded into Q)
        float sc[4][4] = {};
        #pragma unroll 8
        for (int kk = 0; kk < D_; ++kk) {
            const float4 a4 = *(const float4*)&Qst[kk][ty * 4];
            const float4 b4 = *(const float4*)&Kst[kk][tx * 4];
            const float a[4] = {a4.x, a4.y, a4.z, a4.w};
            const float bv[4] = {b4.x, b4.y, b4.z, b4.w};
            #pragma unroll
            for (int i = 0; i < 4; ++i)
                #pragma unroll
                for (int j = 0; j < 4; ++j)
                    sc[i][j] += a[i] * bv[j];
        }
        // Write raw scores transposed: Pst[col][row]
        #pragma unroll
        for (int j = 0; j < 4; ++j)
            #pragma unroll
            for (int i = 0; i < 4; ++i)
                Pst[tx * 4 + j][ty * 4 + i] = sc[i][j];
        __syncthreads();

        // Online softmax, one thread per query row
        if (tid < 64) {
            const int r = tid;
            float rowmax = -1e30f;
            for (int c = 0; c < 64; ++c) rowmax = fmaxf(rowmax, Pst[c][r]);
            const float mold = m_s[r];
            const float mnew = fmaxf(mold, rowmax);
            const float al   = __expf(mold - mnew);
            float sum = 0.0f;
            for (int c = 0; c < 64; ++c) {
                const float p = __expf(Pst[c][r] - mnew);
                Pst[c][r] = p;
                sum += p;
            }
            l_s[r] = l_s[r] * al + sum;
            m_s[r] = mnew;
            alpha_s[r] = al;
        }
        __syncthreads();

        // O update: o = o*alpha + P.V
        float al_i[4];
        #pragma unroll
        for (int i = 0; i < 4; ++i) al_i[i] = alpha_s[ty * 4 + i];
        float pv[4][4] = {};
        #pragma unroll 8
        for (int kk = 0; kk < 64; ++kk) {
            const float4 a4 = *(const float4*)&Pst[kk][ty * 4];  // P^T[kk][r]
            const float4 b4 = *(const float4*)&Vs[kk][tx * 4];   // V[kk][d]
            const float a[4] = {a4.x, a4.y, a4.z, a4.w};
            const float bv[4] = {b4.x, b4.y, b4.z, b4.w};
            #pragma unroll
            for (int i = 0; i < 4; ++i)
                #pragma unroll
                for (int j = 0; j < 4; ++j)
                    pv[i][j] += a[i] * bv[j];
        }
        #pragma unroll
        for (int i = 0; i < 4; ++i)
            #pragma unroll
            for (int j = 0; j < 4; ++j)
                o_acc[i][j] = o_acc[i][j] * al_i[i] + pv[i][j];
        __syncthreads();  // protect Kst/Vs/Pst before next tile
    }

    // Final normalize + store into [B, S, E] layout
    #pragma unroll
    for (int i = 0; i < 4; ++i) {
        const int r = ty * 4 + i;
        const float inv = 1.0f / l_s[r];
        float4 o;
        o.x = o_acc[i][0] * inv;
        o.y = o_acc[i][1] * inv;
        o.z = o_acc[i][2] * inv;
        o.w = o_acc[i][3] * inv;
        *(float4*)(Og + ((size_t)b * S_ + (q0 + r)) * E_ + h * D_ + tx * 4) = o;
    }
}

// ---------------------------------------------------------------------------
extern "C" void kernel_launch(void* const* d_in, const int* in_sizes, int n_in,
                              void* d_out, int out_size, void* d_ws, size_t ws_size,
                              hipStream_t stream) {
    const float* query = (const float*)d_in[0];
    const float* key   = (const float*)d_in[1];
    const float* value = (const float*)d_in[2];
    const float* Wq = (const float*)d_in[3];
    const float* bq = (const float*)d_in[4];
    const float* Wk = (const float*)d_in[5];
    const float* bk = (const float*)d_in[6];
    const float* Wv = (const float*)d_in[7];
    const float* bv = (const float*)d_in[8];
    const float* Wo = (const float*)d_in[9];
    const float* bo = (const float*)d_in[10];
    float* out = (float*)d_out;

    // Workspace: q,k,v head-split [B,H,S,D] + attention output [B,S,E]
    float* ws   = (float*)d_ws;
    const size_t plane = (size_t)M_ * E_;     // 4M floats = 16 MB each
    float* q_ws  = ws;
    float* k_ws  = ws + plane;
    float* v_ws  = ws + 2 * plane;
    float* ao_ws = ws + 3 * plane;            // total 64 MB

    const dim3 gblk(256);
    const dim3 ggrid(E_ / 64, M_ / 64);       // (16, 64)

    gemm_xwt<<<ggrid, gblk, 0, stream>>>(query, Wq, bq, q_ws, 1);
    gemm_xwt<<<ggrid, gblk, 0, stream>>>(key,   Wk, bk, k_ws, 1);
    gemm_xwt<<<ggrid, gblk, 0, stream>>>(value, Wv, bv, v_ws, 1);

    flash_attn<<<dim3(S_ / 64, H_, B_), gblk, 0, stream>>>(q_ws, k_ws, v_ws, ao_ws);

    gemm_xwt<<<ggrid, gblk, 0, stream>>>(ao_ws, Wo, bo, out, 0);
}

// Round 2
// 287.617 us; speedup vs baseline: 4.4434x; 4.4434x over previous
//
#include <hip/hip_runtime.h>

#define B_ 2
#define S_ 2048
#define E_ 1024
#define H_ 16
#define D_ 64
#define M_ (B_*S_)
#define K_ E_

typedef __attribute__((ext_vector_type(8))) short  short8;   // 8 bf16 (4 VGPRs) MFMA frag
typedef __attribute__((ext_vector_type(4))) float  f32x4;    // MFMA acc
typedef __attribute__((ext_vector_type(8))) unsigned short u16x8;
typedef __attribute__((ext_vector_type(4))) unsigned short u16x4;

// fp32 -> bf16 round-to-nearest-even
__device__ __forceinline__ unsigned short f2bf(float f) {
    unsigned u = __float_as_uint(f);
    u += 0x7fffu + ((u >> 16) & 1u);
    return (unsigned short)(u >> 16);
}

// async global->LDS, 16B per lane (dest = wave-uniform base + lane*16)
__device__ __forceinline__ void gl_lds16(const ushort* g, ushort* l) {
    __builtin_amdgcn_global_load_lds((const __attribute__((address_space(1))) void*)g,
                                     (__attribute__((address_space(3))) void*)l,
                                     16, 0, 0);
}

// ---------------------------------------------------------------------------
// fp32 -> bf16 conversion for all inputs in one kernel.
// ws layout (bf16 elems): Xq=0, Xk=4M, Xv=8M, Wq=12M, Wk=13M, Wv=14M, Wo=15M
// ---------------------------------------------------------------------------
__global__ __launch_bounds__(256)
void cvt_all(const float* __restrict__ q, const float* __restrict__ k,
             const float* __restrict__ v, const float* __restrict__ wq,
             const float* __restrict__ wk, const float* __restrict__ wv,
             const float* __restrict__ wo, ushort* __restrict__ dst)
{
    const int bid = blockIdx.x;
    const float* src;
    size_t dof;
    int local;
    if (bid < 6144) {
        const int t = bid >> 11;                     // 2048 blocks per X tensor
        src = (t == 0) ? q : (t == 1) ? k : v;
        dof = (size_t)t * 4194304u;
        local = bid & 2047;
    } else {
        const int r = bid - 6144;
        const int t = r >> 9;                        // 512 blocks per W tensor
        src = (t == 0) ? wq : (t == 1) ? wk : (t == 2) ? wv : wo;
        dof = 12582912u + (size_t)t * 1048576u;
        local = r & 511;
    }
    const size_t idx = (size_t)local * 2048 + threadIdx.x * 8;
    const float4 a = *(const float4*)(src + idx);
    const float4 b = *(const float4*)(src + idx + 4);
    u16x8 o;
    o[0] = f2bf(a.x); o[1] = f2bf(a.y); o[2] = f2bf(a.z); o[3] = f2bf(a.w);
    o[4] = f2bf(b.x); o[5] = f2bf(b.y); o[6] = f2bf(b.z); o[7] = f2bf(b.w);
    *(u16x8*)(dst + dof + idx) = o;
}

// ---------------------------------------------------------------------------
// m97-style MFMA GEMM core: Y = X (MxK) . W^T (NxK), 128x128 tile, BK=32.
// 256 thr = 4 waves (2x2), each wave 64x64 = 4x4 tiles of 16x16x32 MFMA.
// Leaves acc[mt][nt] in C-layout: row=(lane>>4)*4+r, col=lane&15.
// ---------------------------------------------------------------------------
__device__ __forceinline__ void gemm_core(const ushort* __restrict__ X,
                                          const ushort* __restrict__ W,
                                          int m0, int n0,
                                          f32x4 acc[4][4],
                                          ushort* Ast, ushort* Bst)
{
    const int tid  = threadIdx.x;
    const int lane = tid & 63;
    const int w    = tid >> 6;
    const int wm   = w & 1, wn = w >> 1;
    const int r0   = tid >> 2;            // staging row 0..63
    const int c8   = (tid & 3) * 8;       // staging col (elems)

    const f32x4 zero = {0.f, 0.f, 0.f, 0.f};
    #pragma unroll
    for (int mt = 0; mt < 4; ++mt)
        #pragma unroll
        for (int nt = 0; nt < 4; ++nt) acc[mt][nt] = zero;

    const int kb = (lane >> 4) * 8;       // frag k offset within BK=32

    for (int k0 = 0; k0 < K_; k0 += 32) {
        __syncthreads();
        const ushort* ga = X + (size_t)(m0 + r0) * K_ + k0 + c8;
        gl_lds16(ga, Ast + tid * 8);
        gl_lds16(ga + (size_t)64 * K_, Ast + 2048 + tid * 8);
        const ushort* gb = W + (size_t)(n0 + r0) * K_ + k0 + c8;
        gl_lds16(gb, Bst + tid * 8);
        gl_lds16(gb + (size_t)64 * K_, Bst + 2048 + tid * 8);
        __syncthreads();

        short8 af[4], bf[4];
        #pragma unroll
        for (int mt = 0; mt < 4; ++mt)
            af[mt] = *(const short8*)(Ast + (wm * 64 + mt * 16 + (lane & 15)) * 32 + kb);
        #pragma unroll
        for (int nt = 0; nt < 4; ++nt)
            bf[nt] = *(const short8*)(Bst + (wn * 64 + nt * 16 + (lane & 15)) * 32 + kb);
        #pragma unroll
        for (int mt = 0; mt < 4; ++mt)
            #pragma unroll
            for (int nt = 0; nt < 4; ++nt)
                acc[mt][nt] = __builtin_amdgcn_mfma_f32_16x16x32_bf16(af[mt], bf[nt], acc[mt][nt], 0, 0, 0);
    }
}

// ---------------------------------------------------------------------------
// Fused QKV projections. z=0: Q -> [B,H,S,D]; z=1: K -> [B,H,S,D];
// z=2: V -> transposed [B,H,D,S] (so attention PV B-frags are contiguous).
// ---------------------------------------------------------------------------
__global__ __launch_bounds__(256)
void gemm_qkv(const ushort* __restrict__ Xq, const ushort* __restrict__ Xk,
              const ushort* __restrict__ Xv, const ushort* __restrict__ Wq,
              const ushort* __restrict__ Wk, const ushort* __restrict__ Wv,
              const float* __restrict__ bq, const float* __restrict__ bk,
              const float* __restrict__ bv, ushort* __restrict__ Qh,
              ushort* __restrict__ Kh, ushort* __restrict__ Vt)
{
    __shared__ ushort Ast[128 * 32];
    __shared__ ushort Bst[128 * 32];
    const int z = blockIdx.z;
    const ushort* X = (z == 0) ? Xq : (z == 1) ? Xk : Xv;
    const ushort* W = (z == 0) ? Wq : (z == 1) ? Wk : Wv;
    const float* bias = (z == 0) ? bq : (z == 1) ? bk : bv;
    ushort* dst = (z == 0) ? Qh : (z == 1) ? Kh : Vt;

    const int m0 = blockIdx.y * 128, n0 = blockIdx.x * 128;
    f32x4 acc[4][4];
    gemm_core(X, W, m0, n0, acc, Ast, Bst);

    const int lane = threadIdx.x & 63, w = threadIdx.x >> 6;
    const int wm = w & 1, wn = w >> 1;
    float bias4[4];
    #pragma unroll
    for (int nt = 0; nt < 4; ++nt)
        bias4[nt] = bias[n0 + wn * 64 + nt * 16 + (lane & 15)];

    #pragma unroll
    for (int mt = 0; mt < 4; ++mt) {
        const int mrow0 = m0 + wm * 64 + mt * 16 + ((lane >> 4) * 4);
        const int b = mrow0 >> 11;
        const int s0 = mrow0 & (S_ - 1);
        #pragma unroll
        for (int nt = 0; nt < 4; ++nt) {
            const int n = n0 + wn * 64 + nt * 16 + (lane & 15);
            const int h = n >> 6, d = n & 63;
            if (z < 2) {
                #pragma unroll
                for (int r = 0; r < 4; ++r)
                    dst[(((size_t)(b * H_ + h) * S_) + s0 + r) * D_ + d] =
                        f2bf(acc[mt][nt][r] + bias4[nt]);
            } else {
                u16x4 pk;
                #pragma unroll
                for (int r = 0; r < 4; ++r) pk[r] = f2bf(acc[mt][nt][r] + bias4[nt]);
                *(u16x4*)&dst[(((size_t)(b * H_ + h) * D_) + d) * S_ + s0] = pk;
            }
        }
    }
}

// ---------------------------------------------------------------------------
// Final projection: out(fp32) = AO(bf16) . Wo^T + bo
// ---------------------------------------------------------------------------
__global__ __launch_bounds__(256)
void gemm_out(const ushort* __restrict__ X, const ushort* __restrict__ W,
              const float* __restrict__ bias, float* __restrict__ out)
{
    __shared__ ushort Ast[128 * 32];
    __shared__ ushort Bst[128 * 32];
    const int m0 = blockIdx.y * 128, n0 = blockIdx.x * 128;
    f32x4 acc[4][4];
    gemm_core(X, W, m0, n0, acc, Ast, Bst);

    const int lane = threadIdx.x & 63, w = threadIdx.x >> 6;
    const int wm = w & 1, wn = w >> 1;
    float bias4[4];
    #pragma unroll
    for (int nt = 0; nt < 4; ++nt)
        bias4[nt] = bias[n0 + wn * 64 + nt * 16 + (lane & 15)];

    #pragma unroll
    for (int mt = 0; mt < 4; ++mt) {
        const int mrow0 = m0 + wm * 64 + mt * 16 + ((lane >> 4) * 4);
        #pragma unroll
        for (int nt = 0; nt < 4; ++nt) {
            const int n = n0 + wn * 64 + nt * 16 + (lane & 15);
            #pragma unroll
            for (int r = 0; r < 4; ++r)
                out[(size_t)(mrow0 + r) * E_ + n] = acc[mt][nt][r] + bias4[nt];
        }
    }
}

// ---------------------------------------------------------------------------
// MFMA flash attention. Block = (q-tile 64, head, batch), 4 waves.
// Wave w owns q rows [w*16, w*16+16). Computes T = K.Q^T (so softmax state
// lives per-lane: q == lane&15 class; 2 shfl_xor per reduction).
// P round-trips through per-wave LDS (b64 write / b128 read) into A-frag
// layout; PV uses alpha-rescaled O as the MFMA C operand.
// LDS stride 88 elems = 176B: 16B-aligned b128, 2-way banks (free).
// ---------------------------------------------------------------------------
__global__ __launch_bounds__(256)
void flash_mfma(const ushort* __restrict__ Qg, const ushort* __restrict__ Kg,
                const ushort* __restrict__ Vg, ushort* __restrict__ AO)
{
    __shared__ ushort Qs[64][88];
    __shared__ ushort Ks[64][88];
    __shared__ ushort Vs[64][88];      // V^T tile: [d][kv]
    __shared__ ushort Ps[4][16][88];   // per-wave P: [q_local][kv]

    const int tid = threadIdx.x, lane = tid & 63, w = tid >> 6;
    const int q0 = blockIdx.x * 64, h = blockIdx.y, b = blockIdx.z;
    const size_t qk_off = (size_t)(b * H_ + h) * S_ * D_;   // [s][d]
    const size_t vt_off = (size_t)(b * H_ + h) * D_ * S_;   // [d][s]

    // stage Q tile [64 q][64 d]
    {
        const int row = tid >> 3, col = (tid & 7) * 8;
        #pragma unroll
        for (int i = 0; i < 2; ++i)
            *(u16x8*)&Qs[i * 32 + row][col] =
                *(const u16x8*)(Qg + qk_off + (size_t)(q0 + i * 32 + row) * D_ + col);
    }
    __syncthreads();

    // loop-invariant Q B-frags for this wave's 16 q rows
    short8 qb[2];
    #pragma unroll
    for (int kt = 0; kt < 2; ++kt)
        qb[kt] = *(const short8*)&Qs[w * 16 + (lane & 15)][kt * 32 + (lane >> 4) * 8];

    const f32x4 zero = {0.f, 0.f, 0.f, 0.f};
    f32x4 o[4];
    #pragma unroll
    for (int nt = 0; nt < 4; ++nt) o[nt] = zero;
    float mrun = -1e30f, lrun = 0.0f;

    for (int j0 = 0; j0 < S_; j0 += 64) {
        __syncthreads();
        {
            const int row = tid >> 3, col = (tid & 7) * 8;
            #pragma unroll
            for (int i = 0; i < 2; ++i) {
                const int rr = i * 32 + row;
                *(u16x8*)&Ks[rr][col] =
                    *(const u16x8*)(Kg + qk_off + (size_t)(j0 + rr) * D_ + col);
                *(u16x8*)&Vs[rr][col] =
                    *(const u16x8*)(Vg + vt_off + (size_t)rr * S_ + j0 + col);
            }
        }
        __syncthreads();

        // T = K.Q^T : lane holds T[kv = mt*16+(lane>>4)*4+r][q = w*16 + (lane&15)]
        f32x4 t[4];
        #pragma unroll
        for (int mt = 0; mt < 4; ++mt) t[mt] = zero;
        #pragma unroll
        for (int kt = 0; kt < 2; ++kt) {
            #pragma unroll
            for (int mt = 0; mt < 4; ++mt) {
                const short8 ka =
                    *(const short8*)&Ks[mt * 16 + (lane & 15)][kt * 32 + (lane >> 4) * 8];
                t[mt] = __builtin_amdgcn_mfma_f32_16x16x32_bf16(ka, qb[kt], t[mt], 0, 0, 0);
            }
        }

        // online softmax over kv for q-class = lane&15
        float tmax = -1e30f;
        #pragma unroll
        for (int mt = 0; mt < 4; ++mt)
            #pragma unroll
            for (int r = 0; r < 4; ++r) {
                t[mt][r] *= 0.125f;
                tmax = fmaxf(tmax, t[mt][r]);
            }
        tmax = fmaxf(tmax, __shfl_xor(tmax, 16));
        tmax = fmaxf(tmax, __shfl_xor(tmax, 32));
        const float mnew = fmaxf(mrun, tmax);
        const float alpha = __expf(mrun - mnew);
        float psum = 0.f;
        #pragma unroll
        for (int mt = 0; mt < 4; ++mt)
            #pragma unroll
            for (int r = 0; r < 4; ++r) {
                const float p = __expf(t[mt][r] - mnew);
                t[mt][r] = p;
                psum += p;
            }
        psum += __shfl_xor(psum, 16);
        psum += __shfl_xor(psum, 32);
        lrun = lrun * alpha + psum;
        mrun = mnew;

        // P^T (C-layout) -> Ps[q_local][kv] as bf16 (b64 writes)
        #pragma unroll
        for (int mt = 0; mt < 4; ++mt) {
            u16x4 pk;
            #pragma unroll
            for (int r = 0; r < 4; ++r) pk[r] = f2bf(t[mt][r]);
            *(u16x4*)&Ps[w][lane & 15][mt * 16 + (lane >> 4) * 4] = pk;
        }

        // rescale O by alpha of each row's q-class, then PV with O as C operand
        float ar[4];
        #pragma unroll
        for (int r = 0; r < 4; ++r) ar[r] = __shfl(alpha, (lane >> 4) * 4 + r);
        #pragma unroll
        for (int nt = 0; nt < 4; ++nt)
            #pragma unroll
            for (int r = 0; r < 4; ++r) o[nt][r] *= ar[r];

        short8 pa[2];
        #pragma unroll
        for (int kt = 0; kt < 2; ++kt)
            pa[kt] = *(const short8*)&Ps[w][lane & 15][kt * 32 + (lane >> 4) * 8];
        #pragma unroll
        for (int kt = 0; kt < 2; ++kt)
            #pragma unroll
            for (int nt = 0; nt < 4; ++nt) {
                const short8 vb =
                    *(const short8*)&Vs[nt * 16 + (lane & 15)][kt * 32 + (lane >> 4) * 8];
                o[nt] = __builtin_amdgcn_mfma_f32_16x16x32_bf16(pa[kt], vb, o[nt], 0, 0, 0);
            }
    }

    // normalize and store AO [B,S,E] bf16
    float inv[4];
    #pragma unroll
    for (int r = 0; r < 4; ++r) {
        const float lr = __shfl(lrun, (lane >> 4) * 4 + r);
        inv[r] = 1.0f / lr;
    }
    #pragma unroll
    for (int nt = 0; nt < 4; ++nt) {
        const int e = h * 64 + nt * 16 + (lane & 15);
        #pragma unroll
        for (int r = 0; r < 4; ++r) {
            const int s = q0 + w * 16 + (lane >> 4) * 4 + r;
            AO[(size_t)(b * S_ + s) * E_ + e] = f2bf(o[nt][r] * inv[r]);
        }
    }
}

// ---------------------------------------------------------------------------
extern "C" void kernel_launch(void* const* d_in, const int* in_sizes, int n_in,
                              void* d_out, int out_size, void* d_ws, size_t ws_size,
                              hipStream_t stream) {
    const float* query = (const float*)d_in[0];
    const float* key   = (const float*)d_in[1];
    const float* value = (const float*)d_in[2];
    const float* Wq = (const float*)d_in[3];
    const float* bq = (const float*)d_in[4];
    const float* Wk = (const float*)d_in[5];
    const float* bk = (const float*)d_in[6];
    const float* Wv = (const float*)d_in[7];
    const float* bv = (const float*)d_in[8];
    const float* Wo = (const float*)d_in[9];
    const float* bo = (const float*)d_in[10];
    float* out = (float*)d_out;

    ushort* ws = (ushort*)d_ws;
    ushort* Xq  = ws;                      // 4M elems each (bf16)
    ushort* Xk  = ws + 4194304u;
    ushort* Xv  = ws + 8388608u;
    ushort* Wqb = ws + 12582912u;          // 1M elems each
    ushort* Wkb = ws + 13631488u;
    ushort* Wvb = ws + 14680064u;
    ushort* Wob = ws + 15728640u;
    ushort* Qh  = ws + 16777216u;          // [B,H,S,D] bf16
    ushort* Kh  = ws + 20971520u;
    ushort* Vt  = ws + 25165824u;          // [B,H,D,S] bf16
    ushort* AO  = ws + 29360128u;          // [B,S,E]  bf16   (ends at 32M elems = 64MB)

    cvt_all<<<8192, 256, 0, stream>>>(query, key, value, Wq, Wk, Wv, Wo, ws);
    gemm_qkv<<<dim3(8, 32, 3), 256, 0, stream>>>(Xq, Xk, Xv, Wqb, Wkb, Wvb,
                                                 bq, bk, bv, Qh, Kh, Vt);
    flash_mfma<<<dim3(32, 16, 2), 256, 0, stream>>>(Qh, Kh, Vt, AO);
    gemm_out<<<dim3(8, 32, 1), 256, 0, stream>>>(AO, Wob, bo, out);
}